// Round 2
// baseline (659.315 us; speedup 1.0000x reference)
//
#include <hip/hip_runtime.h>
#include <hip/hip_bf16.h>
#include <math.h>

// Problem constants (S,B,L,E) = (4,4,4096,1024), H=8, D=128
#define SS 4
#define BB 4
#define LL 4096
#define EE 1024
#define HH 8
#define DD 128
#define TT (BB*LL)              // 16384 tokens
#define AGG_ELEMS ((long)TT*EE)

using bf16  = __hip_bfloat16;
using bfp2  = __hip_bfloat162;
using bhalf8_t  = __attribute__((ext_vector_type(8))) short;           // 8 bf16
using floatx4_t = __attribute__((ext_vector_type(4))) float;           // MFMA acc
using ushort8_t = __attribute__((ext_vector_type(8))) unsigned short;

__device__ __forceinline__ void gload16(const void* g, void* l) {
  // async global->LDS, 16B/lane; LDS dest is wave-uniform base + lane*16
  __builtin_amdgcn_global_load_lds((const __attribute__((address_space(1))) void*)g,
                                   (__attribute__((address_space(3))) void*)l, 16, 0, 0);
}

// ---- K0: cast Wv, Wout (f32, ExE each) to bf16 -------------------------------
__global__ __launch_bounds__(256) void k_convert(const float* __restrict__ Wv,
                                                 const float* __restrict__ Wo,
                                                 bf16* __restrict__ WvB,
                                                 bf16* __restrict__ WoB) {
  int i = blockIdx.x * 256 + threadIdx.x;
  float4 a = ((const float4*)Wv)[i];
  float4 b = ((const float4*)Wo)[i];
  bfp2 p;
  p.x = __float2bfloat16(a.x); p.y = __float2bfloat16(a.y); ((bfp2*)WvB)[2*i]   = p;
  p.x = __float2bfloat16(a.z); p.y = __float2bfloat16(a.w); ((bfp2*)WvB)[2*i+1] = p;
  p.x = __float2bfloat16(b.x); p.y = __float2bfloat16(b.y); ((bfp2*)WoB)[2*i]   = p;
  p.x = __float2bfloat16(b.z); p.y = __float2bfloat16(b.w); ((bfp2*)WoB)[2*i+1] = p;
}

// ---- K1: q[f] = query . Wq[f,:] + bq[f] --------------------------------------
__global__ __launch_bounds__(256) void k_q(const float* __restrict__ query,
                                           const float* __restrict__ Wq,
                                           const float* __restrict__ bq,
                                           float* __restrict__ q) {
  int lane = threadIdx.x & 63;
  int f = blockIdx.x * 4 + (threadIdx.x >> 6);
  const float* wr = Wq + (long)f * EE;
  float acc = 0.f;
  for (int e = lane; e < EE; e += 64) acc += query[e] * wr[e];
#pragma unroll
  for (int o = 32; o; o >>= 1) acc += __shfl_down(acc, o);
  if (!lane) q[f] = acc + bq[f];
}

// ---- K2: qk[h,e] = scale * sum_d q[h,d] * Wk[h*D+d, e] -----------------------
__global__ __launch_bounds__(256) void k_qk(const float* __restrict__ q,
                                            const float* __restrict__ Wk,
                                            float* __restrict__ qk) {
  int idx = blockIdx.x * 256 + threadIdx.x;
  int h = idx >> 10, e = idx & 1023;
  const float* qh = q + h * DD;
  float acc = 0.f;
  for (int d = 0; d < DD; ++d) acc += qh[d] * Wk[(long)(h * DD + d) * EE + e];
  qk[idx] = acc * 0.088388347648318447f;  // 1/sqrt(128); bk dropped (softmax-invariant)
}

// ---- K3: attention only: logits -> softmax -> attn_ws + weights --------------
// 256 thr = 4 waves, one wave per token, streaming X (no LDS staging of X).
__global__ __launch_bounds__(256) void k_attn(const float* __restrict__ X,
                                              const float* __restrict__ qk,
                                              float* __restrict__ attn_ws,
                                              float* __restrict__ wout) {
  __shared__ float qs[HH * EE];  // 32 KB
#pragma unroll
  for (int i = 0; i < 8; ++i)
    ((float4*)qs)[i * 256 + threadIdx.x] = ((const float4*)qk)[i * 256 + threadIdx.x];
  __syncthreads();
  int lane = threadIdx.x & 63;
  long tok = (long)blockIdx.x * 4 + (threadIdx.x >> 6);
  float acc[HH][SS];
#pragma unroll
  for (int h = 0; h < HH; ++h)
#pragma unroll
    for (int s = 0; s < SS; ++s) acc[h][s] = 0.f;
#pragma unroll
  for (int it = 0; it < 4; ++it) {
    int e0 = it * 256 + lane * 4;
    float4 xv[SS];
#pragma unroll
    for (int s = 0; s < SS; ++s)
      xv[s] = *(const float4*)&X[((long)s * TT + tok) * EE + e0];
#pragma unroll
    for (int h = 0; h < HH; ++h) {
      float4 qv = *(const float4*)&qs[h * EE + e0];
#pragma unroll
      for (int s = 0; s < SS; ++s)
        acc[h][s] += qv.x * xv[s].x + qv.y * xv[s].y + qv.z * xv[s].z + qv.w * xv[s].w;
    }
  }
#pragma unroll
  for (int h = 0; h < HH; ++h)
#pragma unroll
    for (int s = 0; s < SS; ++s)
#pragma unroll
      for (int o = 1; o < 64; o <<= 1) acc[h][s] += __shfl_xor(acc[h][s], o);
  if (lane == 0) {
    float aw[HH][SS];
#pragma unroll
    for (int h = 0; h < HH; ++h) {
      float m = fmaxf(fmaxf(acc[h][0], acc[h][1]), fmaxf(acc[h][2], acc[h][3]));
      float p0 = __expf(acc[h][0] - m), p1 = __expf(acc[h][1] - m);
      float p2 = __expf(acc[h][2] - m), p3 = __expf(acc[h][3] - m);
      float inv = 1.f / (p0 + p1 + p2 + p3);
      aw[h][0] = p0 * inv; aw[h][1] = p1 * inv; aw[h][2] = p2 * inv; aw[h][3] = p3 * inv;
      *(float4*)&attn_ws[tok * 32 + h * 4] = (float4){aw[h][0], aw[h][1], aw[h][2], aw[h][3]};
    }
#pragma unroll
    for (int s = 0; s < SS; ++s) {
      float wsum = 0.125f * (aw[0][s] + aw[1][s] + aw[2][s] + aw[3][s] +
                             aw[4][s] + aw[5][s] + aw[6][s] + aw[7][s]);
      wout[(long)s * TT + tok] = wsum;
    }
  }
}

// ---- K4: fused y-form + ctx-GEMM (Wv) + out-GEMM (Wo), ctx/y never hit HBM ---
// 512 thr = 8 waves; block = 64 tokens; wave w = head w (phase1) / col-slice (phase2).
// LDS: union{ phase1: xs dbuf 2x32KB (f32, 16B-granule XOR swizzle) + y 32KB (bf16),
//             phase2: ctx 128KB (bf16, swizzled) }.
__global__ __launch_bounds__(512, 2) void k_fused(const float* __restrict__ X,
                                                  const float* __restrict__ attn_g,
                                                  const bf16* __restrict__ WvB,
                                                  const bf16* __restrict__ WoB,
                                                  const float* __restrict__ bvp,
                                                  const float* __restrict__ bop,
                                                  float* __restrict__ out) {
  union SMem {
    struct { float xs[2][8192]; unsigned short yb[16384]; } p1;  // 64KB + 32KB
    unsigned short ctx[65536];                                   // 128KB
  };
  __shared__ SMem sm;
  const int tid = threadIdx.x;
  const int w = tid >> 6, lane = tid & 63;
  const int tk = lane & 15, hi = lane >> 4;
  const long t0 = (long)blockIdx.x * 64;
  // y-form thread coords: thread = (t, hh, e4)
  const int ty = tid >> 3, e4 = tid & 3, hh = (tid >> 2) & 1;

  // attn weights for this thread's token, its 4 heads: a4[j] = attn[t][hh*4+j][0..3]
  float4 a4[4];
#pragma unroll
  for (int j = 0; j < 4; ++j)
    a4[j] = *(const float4*)&attn_g[(t0 + ty) * 32 + hh * 16 + j * 4];

  floatx4_t acc[4][8];
#pragma unroll
  for (int mi = 0; mi < 4; ++mi)
#pragma unroll
    for (int ni = 0; ni < 8; ++ni) acc[mi][ni] = (floatx4_t){0.f, 0.f, 0.f, 0.f};

  // async stage of one 32-e chunk of X into xs[buf]; logical granule g stored at
  // position g^(t&7) (inverse-swizzled SOURCE, linear LDS dest per m173/m201)
  auto stage = [&](int c, int buf) {
    float* dst = sm.p1.xs[buf];
#pragma unroll
    for (int i = 0; i < 4; ++i) {
      int aa = i * 8 + w;                 // wave-uniform
      int r = aa * 8 + (lane >> 3);       // row = s*64+t, 256 rows of 128B
      int s = r >> 6, t = r & 63;
      int g = (lane & 7) ^ (t & 7);       // logical 16B-granule for this slot
      gload16(X + ((long)s * TT + t0 + t) * EE + c * 32 + g * 4, dst + aa * 256);
    }
  };

  stage(0, 0);
  __syncthreads();

  for (int c = 0; c < 32; ++c) {
    const float* xsc = sm.p1.xs[c & 1];
    // --- y-form: y[h][t][e] bf16, granule e4 stored at e4^((t>>1)&3) ---
    float4 xlo[4], xhi[4];
#pragma unroll
    for (int s = 0; s < 4; ++s) {
      int row = s * 64 + ty;
      xlo[s] = *(const float4*)&xsc[row * 32 + (((2 * e4) ^ (ty & 7)) * 4)];
      xhi[s] = *(const float4*)&xsc[row * 32 + (((2 * e4 + 1) ^ (ty & 7)) * 4)];
    }
#pragma unroll
    for (int j = 0; j < 4; ++j) {
      int h = hh * 4 + j;
      float u[8];
#pragma unroll
      for (int k = 0; k < 4; ++k) {
        u[k]     = a4[j].x * ((&xlo[0].x)[k]) + a4[j].y * ((&xlo[1].x)[k]) +
                   a4[j].z * ((&xlo[2].x)[k]) + a4[j].w * ((&xlo[3].x)[k]);
        u[k + 4] = a4[j].x * ((&xhi[0].x)[k]) + a4[j].y * ((&xhi[1].x)[k]) +
                   a4[j].z * ((&xhi[2].x)[k]) + a4[j].w * ((&xhi[3].x)[k]);
      }
      ushort8_t o;
#pragma unroll
      for (int k = 0; k < 8; ++k) {
        bf16 b = __float2bfloat16(u[k]);
        o[k] = *(unsigned short*)&b;
      }
      *(ushort8_t*)&sm.p1.yb[(h * 64 + ty) * 32 + ((e4 ^ ((ty >> 1) & 3)) * 8)] = o;
    }
    __syncthreads();                       // y chunk visible
    if (c + 1 < 32) stage(c + 1, (c + 1) & 1);  // overlap with GEMM below
    // --- ctx GEMM for head w: A = y (LDS), B = Wv rows (global, L2-hot) ---
    bhalf8_t af[4];
#pragma unroll
    for (int mi = 0; mi < 4; ++mi) {
      int t = mi * 16 + tk;
      af[mi] = *(const bhalf8_t*)&sm.p1.yb[(w * 64 + t) * 32 + ((hi ^ ((t >> 1) & 3)) * 8)];
    }
#pragma unroll
    for (int ni = 0; ni < 8; ++ni) {
      bhalf8_t bfr = *(const bhalf8_t*)&WvB[(long)(w * 128 + ni * 16 + tk) * EE + c * 32 + hi * 8];
#pragma unroll
      for (int mi = 0; mi < 4; ++mi)
        acc[mi][ni] = __builtin_amdgcn_mfma_f32_16x16x32_bf16(af[mi], bfr, acc[mi][ni], 0, 0, 0);
    }
    __syncthreads();                       // drains stage(c+1); y reads done
  }

  // --- phase-1 epilogue: acc (+bv) -> ctx LDS, bf16, 16B-granule XOR(t&7) ---
#pragma unroll
  for (int mi = 0; mi < 4; ++mi)
#pragma unroll
    for (int ni = 0; ni < 8; ++ni) {
      int f = w * 128 + ni * 16 + tk;
      float bv = bvp[f];
#pragma unroll
      for (int r = 0; r < 4; ++r) {
        int t = mi * 16 + hi * 4 + r;
        bf16 b = __float2bfloat16(acc[mi][ni][r] + bv);
        sm.ctx[t * 1024 + (f >> 6) * 64 + ((((f >> 3) & 7) ^ (t & 7)) * 8) + (f & 7)] =
            *(unsigned short*)&b;
      }
    }
  __syncthreads();

  // --- phase 2: agg = ctx @ Wo^T + bo; wave w owns output cols w*128..+127 ---
#pragma unroll
  for (int mi = 0; mi < 4; ++mi)
#pragma unroll
    for (int ni = 0; ni < 8; ++ni) acc[mi][ni] = (floatx4_t){0.f, 0.f, 0.f, 0.f};
  for (int c2 = 0; c2 < 16; ++c2) {
#pragma unroll
    for (int kk = 0; kk < 2; ++kk) {
      bhalf8_t af2[4];
#pragma unroll
      for (int mi = 0; mi < 4; ++mi) {
        int t = mi * 16 + tk;
        af2[mi] = *(const bhalf8_t*)&sm.ctx[t * 1024 + c2 * 64 + (((kk * 4 + hi) ^ (t & 7)) * 8)];
      }
#pragma unroll
      for (int ni = 0; ni < 8; ++ni) {
        bhalf8_t bfr = *(const bhalf8_t*)&WoB[(long)(w * 128 + ni * 16 + tk) * EE + c2 * 64 + kk * 32 + hi * 8];
#pragma unroll
        for (int mi = 0; mi < 4; ++mi)
          acc[mi][ni] = __builtin_amdgcn_mfma_f32_16x16x32_bf16(af2[mi], bfr, acc[mi][ni], 0, 0, 0);
      }
    }
  }
#pragma unroll
  for (int mi = 0; mi < 4; ++mi)
#pragma unroll
    for (int ni = 0; ni < 8; ++ni) {
      int f = w * 128 + ni * 16 + tk;
      float bo = bop[f];
#pragma unroll
      for (int r = 0; r < 4; ++r) {
        int t = mi * 16 + hi * 4 + r;
        out[(t0 + t) * EE + f] = acc[mi][ni][r] + bo;
      }
    }
}

extern "C" void kernel_launch(void* const* d_in, const int* in_sizes, int n_in,
                              void* d_out, int out_size, void* d_ws, size_t ws_size,
                              hipStream_t stream) {
  const float* SO  = (const float*)d_in[0];  // (S,B,L,E)
  const float* SQ  = (const float*)d_in[1];  // (1,1,E)
  const float* IPW = (const float*)d_in[2];  // (3E,E)
  const float* IPB = (const float*)d_in[3];  // (3E,)
  const float* OPW = (const float*)d_in[4];  // (E,E)
  const float* OPB = (const float*)d_in[5];  // (E,)
  float* out = (float*)d_out;                // aggregated (B,L,E) then weights (S,B,L)
  char* ws = (char*)d_ws;

  size_t off = 0;
  auto alloc = [&](size_t bytes) -> void* {
    void* p = ws + off;
    off = (off + bytes + 255) & ~(size_t)255;
    return p;
  };
  float* q    = (float*)alloc((size_t)EE * 4);
  float* qk   = (float*)alloc((size_t)HH * EE * 4);
  float* attn = (float*)alloc((size_t)TT * 32 * 4);      // 2 MB
  bf16*  WvB  = (bf16*) alloc((size_t)EE * EE * 2);      // 2 MB
  bf16*  WoB  = (bf16*) alloc((size_t)EE * EE * 2);      // 2 MB

  k_convert<<<EE * EE / 1024, 256, 0, stream>>>(IPW + 2 * EE * EE, OPW, WvB, WoB);
  k_q<<<EE / 4, 256, 0, stream>>>(SQ, IPW, IPB, q);
  k_qk<<<HH * EE / 256, 256, 0, stream>>>(q, IPW + EE * EE, qk);
  k_attn<<<TT / 4, 256, 0, stream>>>(SO, qk, attn, out + AGG_ELEMS);
  k_fused<<<TT / 64, 512, 0, stream>>>(SO, attn, WvB, WoB, IPB + 2 * EE, OPB, out);
}